// Round 10
// baseline (72.977 us; speedup 1.0000x reference)
//
#include <hip/hip_runtime.h>

#define NN     4096
#define TT     3
#define DD     20
#define EE     131072
#define ADIM   128
#define NEG    0.2f
#define NEDGE  (TT * EE)               // 393216 edges
#define NINST  (2 * NEDGE)             // 786432 directed instances
#define NB     256                     // histogram/scatter blocks
#define IPB    (NINST / NB)            // 3072 instances per block
#define CAP    512                     // fixed segment per row (max occupancy ~260)

// ---- k_hist: per-block LDS row-histogram (histo[blk][row]) + fused s0 init --
__global__ __launch_bounds__(256) void k_hist(const int* __restrict__ el,
                                              unsigned int* __restrict__ histo,
                                              const float* __restrict__ inputs,
                                              const float* __restrict__ lin_w,
                                              const float* __restrict__ lin_b,
                                              float* __restrict__ s0) {
    __shared__ unsigned int h[NN];
    int tid = threadIdx.x, bid = blockIdx.x;
    for (int i = tid; i < NN; i += 256) h[i] = 0u;
    __syncthreads();
    int base = bid * IPB;
    #pragma unroll
    for (int k = 0; k < IPB / 256; k++) {          // 12 iters
        int inst = base + k * 256 + tid;
        int edge = inst >> 1, dir = inst & 1;
        int t = edge >> 17;                        // EE = 2^17
        int e = edge & (EE - 1);
        unsigned int a = (unsigned int)el[(t * 2) * EE + e];
        unsigned int b = (unsigned int)el[(t * 2 + 1) * EE + e];
        unsigned int row = dir ? b : a;
        atomicAdd(&h[row], 1u);
    }
    __syncthreads();
    for (int i = tid; i < NN; i += 256) histo[bid * NN + i] = h[i];  // coalesced

    // fused: s0 = inputs @ lin_w.T + lin_b   (1024 waves x 4 rows)
    int wid = tid >> 6, lane = tid & 63;
    int wg = bid * 4 + wid;                        // 0..1023
    #pragma unroll
    for (int r = 0; r < 4; r++) {
        int row = wg * 4 + r;
        const float* rp = inputs + row * ADIM;
        float v = rp[lane] * lin_w[lane] + rp[lane + 64] * lin_w[lane + 64];
        #pragma unroll
        for (int off = 32; off > 0; off >>= 1) v += __shfl_down(v, off);
        if (lane == 0) s0[row] = v + lin_b[0];
    }
}

// ---- k_prefix: wave per row — exclusive scan across the 256 blocks ----------
// lane l holds blocks 4l..4l+3; in-place bases + bintotal. 4096 waves total.
__global__ __launch_bounds__(256) void k_prefix(unsigned int* __restrict__ histo,
                                                unsigned int* __restrict__ bintotal) {
    int tid = threadIdx.x, wid = tid >> 6, lane = tid & 63;
    int row = blockIdx.x * 4 + wid;                // 1024 blocks x 4 waves
    unsigned int h0 = histo[(4 * lane + 0) * NN + row];
    unsigned int h1 = histo[(4 * lane + 1) * NN + row];
    unsigned int h2 = histo[(4 * lane + 2) * NN + row];
    unsigned int h3 = histo[(4 * lane + 3) * NN + row];
    unsigned int s = h0 + h1 + h2 + h3;
    unsigned int p = s;                            // wave-inclusive scan
    #pragma unroll
    for (int off = 1; off < 64; off <<= 1) {
        unsigned int t = __shfl_up(p, off);
        if (lane >= off) p += t;
    }
    unsigned int e = p - s;                        // exclusive base
    histo[(4 * lane + 0) * NN + row] = e;
    histo[(4 * lane + 1) * NN + row] = e + h0;
    histo[(4 * lane + 2) * NN + row] = e + h0 + h1;
    histo[(4 * lane + 3) * NN + row] = e + h0 + h1 + h2;
    if (lane == 63) bintotal[row] = p;
}

// ---- k_scat: ranked scatter into fixed row segments (LDS base+rank) ---------
__global__ __launch_bounds__(256) void k_scat(const int* __restrict__ el,
                                              const unsigned int* __restrict__ histo,
                                              unsigned short* __restrict__ bucket) {
    __shared__ unsigned int c[NN];
    int tid = threadIdx.x, bid = blockIdx.x;
    for (int i = tid; i < NN; i += 256) c[i] = histo[bid * NN + i];  // block bases
    __syncthreads();
    int base = bid * IPB;
    #pragma unroll
    for (int k = 0; k < IPB / 256; k++) {
        int inst = base + k * 256 + tid;
        int edge = inst >> 1, dir = inst & 1;
        int t = edge >> 17;
        int e = edge & (EE - 1);
        unsigned int a = (unsigned int)el[(t * 2) * EE + e];
        unsigned int b = (unsigned int)el[(t * 2 + 1) * EE + e];
        unsigned int row = dir ? b : a;
        unsigned int col = dir ? a : b;
        unsigned int r = atomicAdd(&c[row], 1u);   // absolute rank within row
        if (r < CAP)
            bucket[row * CAP + r] = (unsigned short)(col | ((unsigned int)t << 12));
    }
}

// ---- k_l0: per-row LDS nibble-mask dedup + layer 0 + compact CSR emit -------
__global__ __launch_bounds__(256) void k_l0(const unsigned int* __restrict__ bintotal,
                                            const unsigned short* __restrict__ bucket,
                                            unsigned int* __restrict__ cnt2,
                                            unsigned short* __restrict__ entries2,
                                            const float* __restrict__ s_in,
                                            const float* __restrict__ att_w,
                                            const float* __restrict__ edge_emb,
                                            float* __restrict__ s_out) {
    __shared__ unsigned int mask[4][512];          // 2 KB nibble-mask per wave/row
    __shared__ float lut0[8], lut1[8], wc[4], Sred[4];
    int tid = threadIdx.x, wid = tid >> 6, lane = tid & 63;

    if (tid < 16) {                                // layer 0 constants
        int h = tid >> 3, m = tid & 7;
        const float* w = att_w + h * (DD + 2);
        float e0 = 0.f, e1 = 0.f, e2 = 0.f;
        #pragma unroll
        for (int d = 0; d < DD; d++) {
            float wd = w[1 + d];
            e0 += edge_emb[0 * DD + d] * wd;
            e1 += edge_emb[1 * DD + d] * wd;
            e2 += edge_emb[2 * DD + d] * wd;
        }
        float l = (m & 1 ? e0 : 0.f) + (m & 2 ? e1 : 0.f) + (m & 4 ? e2 : 0.f);
        if (h) lut1[m] = l; else lut0[m] = l;
        if (m == 0) { wc[h] = w[0]; wc[2 + h] = w[DD + 1]; }
    }

    float ps = 0.f;                                // S = sum(s_in), deterministic
    for (int j = tid; j < NN; j += 256) ps += s_in[j];
    #pragma unroll
    for (int off = 32; off > 0; off >>= 1) ps += __shfl_down(ps, off);
    if (lane == 0) Sred[wid] = ps;

    for (int i = lane; i < 512; i += 64) mask[wid][i] = 0u;
    int row = blockIdx.x * 4 + wid;
    unsigned int n = min(bintotal[row], (unsigned int)CAP);
    const unsigned short* brow = bucket + (size_t)row * CAP;
    for (unsigned int i = lane; i < n; i += 64) {
        unsigned int v = brow[i];
        unsigned int col = v & 0xFFFu, t = v >> 12;
        atomicOr(&mask[wid][col >> 3], 1u << (((col & 7u) << 2) + t));
    }
    __syncthreads();                               // covers lut/Sred/mask
    float S = Sred[0] + Sred[1] + Sred[2] + Sred[3];

    float si = s_in[row];
    float a0 = wc[0] * si, a1 = wc[1] * si;
    float b0 = wc[2],      b1 = wc[3];
    unsigned short* erow = entries2 + (size_t)row * CAP;

    float num0 = 0.f, den0 = 0.f, num1 = 0.f, den1 = 0.f;
    unsigned int base = 0;
    #pragma unroll
    for (int k = 0; k < 8; k++) {                  // 512 words, 8 per lane
        unsigned int w = mask[wid][k * 64 + lane];
        unsigned int y = w | (w >> 1); y |= (y >> 2); y &= 0x11111111u;
        unsigned int cc = __popc(y);
        unsigned int p = cc;                       // wave-inclusive scan
        #pragma unroll
        for (int off = 1; off < 64; off <<= 1) {
            unsigned int v = __shfl_up(p, off);
            if (lane >= off) p += v;
        }
        unsigned int pos = base + (p - cc);        // exclusive prefix
        if (w) {
            int jb = (k * 64 + lane) << 3;
            #pragma unroll
            for (int kk = 0; kk < 8; kk++) {
                unsigned int nib = (w >> (kk * 4)) & 0xFu;
                if (!nib) continue;
                int j = jb + kk;
                float c2 = (float)__popc(nib);
                float sj = s_in[j];
                float l0 = c2 * (a0 + b0 * sj) + lut0[nib];
                l0 = (l0 > 0.f) ? l0 : NEG * l0;
                float x0 = __expf(l0) - 1.0f;
                num0 += x0 * sj; den0 += x0;
                float l1 = c2 * (a1 + b1 * sj) + lut1[nib];
                l1 = (l1 > 0.f) ? l1 : NEG * l1;
                float x1 = __expf(l1) - 1.0f;
                num1 += x1 * sj; den1 += x1;
                erow[pos++] = (unsigned short)(j | (nib << 12));
            }
        }
        base += __shfl(p, 63);
    }
    if (lane == 0) cnt2[row] = base;

    #pragma unroll
    for (int off = 32; off > 0; off >>= 1) {
        num0 += __shfl_down(num0, off); den0 += __shfl_down(den0, off);
        num1 += __shfl_down(num1, off); den1 += __shfl_down(den1, off);
    }
    if (lane == 0) {
        float o0 = (S + num0) / ((float)NN + den0);
        float o1 = (S + num1) / ((float)NN + den1);
        s_out[row] = 0.5f * (o0 + o1);
    }
}

// ---- k_l1: layer 1 over compact CSR (row per wave) --------------------------
__global__ __launch_bounds__(256) void k_l1(const unsigned int* __restrict__ cnt2,
                                            const unsigned short* __restrict__ entries2,
                                            const float* __restrict__ s_in,
                                            const float* __restrict__ att_w,
                                            const float* __restrict__ edge_emb,
                                            float* __restrict__ s_out) {
    __shared__ float lut0[8], lut1[8], wc[4], Sred[4];
    int tid = threadIdx.x;

    if (tid < 16) {                                // layer 1 constants
        int h = tid >> 3, m = tid & 7;
        const float* w = att_w + (2 + h) * (DD + 2);
        float e0 = 0.f, e1 = 0.f, e2 = 0.f;
        #pragma unroll
        for (int d = 0; d < DD; d++) {
            float wd = w[1 + d];
            e0 += edge_emb[0 * DD + d] * wd;
            e1 += edge_emb[1 * DD + d] * wd;
            e2 += edge_emb[2 * DD + d] * wd;
        }
        float l = (m & 1 ? e0 : 0.f) + (m & 2 ? e1 : 0.f) + (m & 4 ? e2 : 0.f);
        if (h) lut1[m] = l; else lut0[m] = l;
        if (m == 0) { wc[h] = w[0]; wc[2 + h] = w[DD + 1]; }
    }

    float ps = 0.f;
    for (int j = tid; j < NN; j += 256) ps += s_in[j];
    #pragma unroll
    for (int off = 32; off > 0; off >>= 1) ps += __shfl_down(ps, off);
    int wid = tid >> 6, lane = tid & 63;
    if (lane == 0) Sred[wid] = ps;
    __syncthreads();
    float S = Sred[0] + Sred[1] + Sred[2] + Sred[3];

    int row = blockIdx.x * 4 + wid;
    float si = s_in[row];
    float a0 = wc[0] * si, a1 = wc[1] * si;
    float b0 = wc[2],      b1 = wc[3];
    unsigned int n = cnt2[row];
    const unsigned short* ent = entries2 + (size_t)row * CAP;

    float num0 = 0.f, den0 = 0.f, num1 = 0.f, den1 = 0.f;
    for (unsigned int i = lane; i < n; i += 64) {
        unsigned int v = ent[i];
        unsigned int j = v & 0xFFFu, nib = v >> 12;
        float c  = (float)__popc(nib);
        float sj = s_in[j];
        float l0 = c * (a0 + b0 * sj) + lut0[nib];
        l0 = (l0 > 0.f) ? l0 : NEG * l0;
        float x0 = __expf(l0) - 1.0f;
        num0 += x0 * sj; den0 += x0;
        float l1 = c * (a1 + b1 * sj) + lut1[nib];
        l1 = (l1 > 0.f) ? l1 : NEG * l1;
        float x1 = __expf(l1) - 1.0f;
        num1 += x1 * sj; den1 += x1;
    }

    #pragma unroll
    for (int off = 32; off > 0; off >>= 1) {
        num0 += __shfl_down(num0, off); den0 += __shfl_down(den0, off);
        num1 += __shfl_down(num1, off); den1 += __shfl_down(den1, off);
    }
    if (lane == 0) {
        float o0 = (S + num0) / ((float)NN + den0);
        float o1 = (S + num1) / ((float)NN + den1);
        s_out[row] = 0.5f * (o0 + o1);
    }
}

// ---- host-side launcher ------------------------------------------------------
extern "C" void kernel_launch(void* const* d_in, const int* in_sizes, int n_in,
                              void* d_out, int out_size, void* d_ws, size_t ws_size,
                              hipStream_t stream) {
    const float* inputs   = (const float*)d_in[0];
    const float* lin_w    = (const float*)d_in[1];
    const float* lin_b    = (const float*)d_in[2];
    const float* edge_emb = (const float*)d_in[3];
    const float* att_w    = (const float*)d_in[4];
    const int*   el       = (const int*)d_in[5];
    float* out = (float*)d_out;

    char* ws = (char*)d_ws;
    unsigned int*   histo    = (unsigned int*)ws;                         // 4 MB
    unsigned int*   bintotal = (unsigned int*)(ws + 4194304);             // 16 KB
    unsigned short* bucket   = (unsigned short*)(ws + 4210688);           // 4 MB
    unsigned short* entries2 = (unsigned short*)(ws + 8404992);           // 4 MB
    unsigned int*   cnt2     = (unsigned int*)(ws + 12599296);            // 16 KB
    float*          s0       = (float*)(ws + 12615680);                   // 16 KB
    float*          s1       = (float*)(ws + 12632064);                   // 16 KB

    k_hist  <<<NB, 256, 0, stream>>>(el, histo, inputs, lin_w, lin_b, s0);
    k_prefix<<<1024, 256, 0, stream>>>(histo, bintotal);
    k_scat  <<<NB, 256, 0, stream>>>(el, histo, bucket);
    k_l0    <<<1024, 256, 0, stream>>>(bintotal, bucket, cnt2, entries2,
                                       s0, att_w, edge_emb, s1);
    k_l1    <<<1024, 256, 0, stream>>>(cnt2, entries2, s1, att_w, edge_emb, out);
}